// Round 8
// baseline (274.955 us; speedup 1.0000x reference)
//
#include <hip/hip_runtime.h>
#include <hip/hip_bf16.h>

typedef unsigned short ushort_t;
typedef unsigned int uint_t;
typedef __attribute__((ext_vector_type(8))) short short8;
typedef __attribute__((ext_vector_type(4))) float f32x4;

__device__ __forceinline__ ushort_t f2bf(float f) {
    uint_t u = __float_as_uint(f);
    uint_t r = (u + 0x7FFFu + ((u >> 16) & 1u)) >> 16;
    return (ushort_t)r;
}
__device__ __forceinline__ float bf2f_lo(uint_t u) { return __uint_as_float(u << 16); }
__device__ __forceinline__ float bf2f_hi(uint_t u) { return __uint_as_float(u & 0xffff0000u); }
// hi bf16 with low 16 bits left as extra-mantissa garbage (<=2^-9 relative).
__device__ __forceinline__ float bf2f_hi_fast(uint_t u) { return __uint_as_float(u); }

#define BSH 8
#define BCK 256
#define CSR_CAP 6144
#define EPB 4096   // edges per histogram/scatter block

// ---------------------------------------------------------------------------
// prep_kernel: blocks 0..34 build the 4 B-fragment tables (MFMA layout),
// blocks 35.. write per-block bucket histograms (NO global atomics).
// ---------------------------------------------------------------------------
__global__ void prep_kernel(const float* __restrict__ W_in,
                            const float* __restrict__ W0, const float* __restrict__ as0,
                            const float* __restrict__ ad0,
                            const float* __restrict__ W1, const float* __restrict__ as1,
                            const float* __restrict__ ad1,
                            const float* __restrict__ W2, const float* __restrict__ as2,
                            const float* __restrict__ ad2,
                            ushort_t* __restrict__ BfIn, ushort_t* __restrict__ Bf0,
                            ushort_t* __restrict__ Bf1, ushort_t* __restrict__ Bf2,
                            const int* __restrict__ ei, int* __restrict__ bhist,
                            int E, int N) {
    __shared__ int hist[256];
    int b = blockIdx.x;
    if (b < 35) {
        const float *W, *a_s, *a_d;
        ushort_t* Bf;
        int H, NT, nt;
        if (b < 8)       { W = W_in; a_s = nullptr; a_d = nullptr; Bf = BfIn; H = 0; NT = 8; nt = b; }
        else if (b < 17) { W = W0; a_s = as0; a_d = ad0; Bf = Bf0; H = 4; NT = 9; nt = b - 8; }
        else if (b < 26) { W = W1; a_s = as1; a_d = ad1; Bf = Bf1; H = 4; NT = 9; nt = b - 17; }
        else             { W = W2; a_s = as2; a_d = ad2; Bf = Bf2; H = 1; NT = 9; nt = b - 26; }
        int l = threadIdx.x & 63;
        int ks = threadIdx.x >> 6;
        int kb = ks * 32 + (l >> 4) * 8;
        int col = l & 15;
        ushort_t v[8];
        if (nt < 8) {
#pragma unroll
            for (int j = 0; j < 8; ++j)
                v[j] = f2bf(W[(size_t)(kb + j) * 128 + nt * 16 + col]);
        } else {
#pragma unroll
            for (int j = 0; j < 8; ++j) {
                int k = kb + j;
                float s = 0.f;
                if (H == 4) {
                    if (col < 4) {
                        for (int c = 0; c < 32; ++c)
                            s += W[(size_t)k * 128 + col * 32 + c] * a_s[col * 32 + c];
                    } else if (col < 8) {
                        int h = col - 4;
                        for (int c = 0; c < 32; ++c)
                            s += W[(size_t)k * 128 + h * 32 + c] * a_d[h * 32 + c];
                    }
                } else {
                    if (col == 0) {
                        for (int c = 0; c < 128; ++c) s += W[(size_t)k * 128 + c] * a_s[c];
                    } else if (col == 1) {
                        for (int c = 0; c < 128; ++c) s += W[(size_t)k * 128 + c] * a_d[c];
                    }
                }
                v[j] = f2bf(s);
            }
        }
        uint4 u;
        u.x = (uint_t)v[0] | ((uint_t)v[1] << 16);
        u.y = (uint_t)v[2] | ((uint_t)v[3] << 16);
        u.z = (uint_t)v[4] | ((uint_t)v[5] << 16);
        u.w = (uint_t)v[6] | ((uint_t)v[7] << 16);
        *(uint4*)(Bf + ((size_t)(ks * NT + nt) * 64 + l) * 8) = u;
    } else {
        int tid = threadIdx.x;
        int blk = b - 35;
        hist[tid] = 0;
        __syncthreads();
        int base = blk * EPB;
        int Etot = E + N;
#pragma unroll
        for (int r = 0; r < EPB / 256; ++r) {
            int i = base + r * 256 + tid;
            if (i < Etot) {
                int dst = (i < E) ? ei[E + i] : (i - E);
                atomicAdd(&hist[dst >> BSH], 1);
            }
        }
        __syncthreads();
        bhist[blk * 256 + tid] = hist[tid];
    }
}

// ---------------------------------------------------------------------------
// csr_scan: thread t owns bucket t. Within-bucket prefix over blocks ->
// obase[blk][t]; wave-scan of bucket totals -> gbase (exclusive).
// ---------------------------------------------------------------------------
__global__ void csr_scan(const int* __restrict__ bhist, int* __restrict__ obase,
                         int* __restrict__ gbase, int* __restrict__ rowp,
                         int NBLK, int N, int Etot) {
    __shared__ int ws[4];
    int t = threadIdx.x;
    int run = 0;
    for (int blk = 0; blk < NBLK; ++blk) {
        int v = bhist[blk * 256 + t];
        obase[blk * 256 + t] = run;
        run += v;
    }
    int lane = t & 63, w = t >> 6;
    int x = run;
#pragma unroll
    for (int off = 1; off < 64; off <<= 1) {
        int t2 = __shfl_up(x, off, 64);
        if (lane >= off) x += t2;
    }
    if (lane == 63) ws[w] = x;
    __syncthreads();
    int add = 0;
    for (int j = 0; j < w; ++j) add += ws[j];
    int excl = add + x - run;
    gbase[t] = excl;
    if (t == 0) {
        gbase[256] = Etot;
        rowp[N] = Etot;
    }
}

// ---------------------------------------------------------------------------
// csr_scatter: LDS-only atomics; global positions pre-assigned per block.
// ---------------------------------------------------------------------------
__global__ void csr_scatter(const int* __restrict__ ei, const int* __restrict__ gbase,
                            const int* __restrict__ obase, uint2* __restrict__ pairs,
                            int E, int N) {
    __shared__ int cur[256];
    int tid = threadIdx.x;
    int blk = blockIdx.x;
    cur[tid] = gbase[tid] + obase[blk * 256 + tid];
    __syncthreads();
    int base = blk * EPB;
    int Etot = E + N;
#pragma unroll
    for (int r = 0; r < EPB / 256; ++r) {
        int i = base + r * 256 + tid;
        if (i < Etot) {
            int src = (i < E) ? ei[i] : (i - E);
            int dst = (i < E) ? ei[E + i] : (i - E);
            int pos = atomicAdd(&cur[dst >> BSH], 1);
            uint2 p;
            p.x = (uint_t)src;
            p.y = (uint_t)dst;
            pairs[pos] = p;
        }
    }
}

__global__ void bucket_csr(const uint2* __restrict__ pairs, const int* __restrict__ gbase,
                           int* __restrict__ rowp, int* __restrict__ csrc, int N) {
    __shared__ int cnt[256];
    __shared__ int ws[4];
    __shared__ int stage[CSR_CAP];
    int b = blockIdx.x, tid = threadIdx.x;
    int eBeg = gbase[b], eEnd = gbase[b + 1];
    int M = eEnd - eBeg;
    cnt[tid] = 0;
    __syncthreads();
    for (int t = tid; t < M; t += 256) {
        uint2 pr = pairs[eBeg + t];
        atomicAdd(&cnt[pr.y & (BCK - 1)], 1);
    }
    __syncthreads();
    int v = cnt[tid];
    int lane = tid & 63, w = tid >> 6;
    int x = v;
#pragma unroll
    for (int off = 1; off < 64; off <<= 1) {
        int t2 = __shfl_up(x, off, 64);
        if (lane >= off) x += t2;
    }
    if (lane == 63) ws[w] = x;
    __syncthreads();
    int add = 0;
    for (int j = 0; j < w; ++j) add += ws[j];
    int excl = add + x - v;
    int node = (b << BSH) + tid;
    if (node < N) rowp[node] = eBeg + excl;
    __syncthreads();
    cnt[tid] = excl;
    __syncthreads();
    for (int t = tid; t < M; t += 256) {
        uint2 pr = pairs[eBeg + t];
        int pos = atomicAdd(&cnt[pr.y & (BCK - 1)], 1);
        if (pos < CSR_CAP) stage[pos] = (int)pr.x;
        else csrc[eBeg + pos] = (int)pr.x;
    }
    __syncthreads();
    int lim = (M < CSR_CAP) ? M : CSR_CAP;
    for (int t = tid; t < lim; t += 256) csrc[eBeg + t] = stage[t];
}

// ---------------------------------------------------------------------------
// MFMA GEMM: TWO 16-row tiles per wave; B staged in LDS per block.
// ---------------------------------------------------------------------------
template <int MODE>
__device__ __forceinline__ void gemm_epilogue(f32x4* acc, int r0, int lg, int lc,
                                              const float* bias, ushort_t* outB,
                                              float* alS, float* alD) {
    if (MODE == 0) {
#pragma unroll
        for (int r = 0; r < 4; ++r) {
            int row = r0 + lg * 4 + r;
            ushort_t* op = outB + (size_t)row * 128 + lc;
#pragma unroll
            for (int nt = 0; nt < 8; ++nt) {
                float v = fmaxf(acc[nt][r] + bias[nt * 16 + lc], 0.f);
                op[nt * 16] = f2bf(v);
            }
        }
    } else {
#pragma unroll
        for (int r = 0; r < 4; ++r) {
            int row = r0 + lg * 4 + r;
            ushort_t* op = outB + (size_t)row * 128 + lc;
#pragma unroll
            for (int nt = 0; nt < 8; ++nt) op[nt * 16] = f2bf(acc[nt][r]);
            float lv = acc[8][r];
            if (MODE == 1) {
                if (lc < 4) alS[(size_t)row * 4 + lc] = lv;
                else if (lc < 8) alD[(size_t)row * 4 + (lc - 4)] = lv;
            } else {
                if (lc == 0) alS[row] = lv;
                else if (lc == 1) alD[row] = lv;
            }
        }
    }
}

template <int MODE>
__launch_bounds__(256)
__global__ void gemm_mfma(const float* __restrict__ Af, const ushort_t* __restrict__ Ab,
                          const ushort_t* __restrict__ Bf, const float* __restrict__ bias,
                          ushort_t* __restrict__ outB, float* __restrict__ alS,
                          float* __restrict__ alD, int M) {
    const int NT = (MODE == 0) ? 8 : 9;
    __shared__ ushort_t Bs[4 * 9 * 64 * 8];
    {
        const int tot = 4 * NT * 64;
        for (int t = threadIdx.x; t < tot; t += 256)
            ((uint4*)Bs)[t] = ((const uint4*)Bf)[t];
    }
    __syncthreads();

    int wid = threadIdx.x >> 6, l = threadIdx.x & 63;
    int lg = l >> 4, lc = l & 15;
    int r0 = (blockIdx.x * 4 + wid) * 32;
    if (r0 >= M) return;
    bool has1 = (r0 + 16) < M;
    int rowA0 = r0 + lc;
    int rowA1 = has1 ? (r0 + 16 + lc) : rowA0;

    f32x4 acc0[9], acc1[9];
#pragma unroll
    for (int nt = 0; nt < NT; ++nt) {
        acc0[nt] = (f32x4){0.f, 0.f, 0.f, 0.f};
        acc1[nt] = (f32x4){0.f, 0.f, 0.f, 0.f};
    }

#pragma unroll
    for (int ks = 0; ks < 4; ++ks) {
        int k0 = ks * 32 + lg * 8;
        short8 af0, af1;
        if (MODE == 0) {
            const float* ap0 = Af + (size_t)rowA0 * 128 + k0;
            const float* ap1 = Af + (size_t)rowA1 * 128 + k0;
            float4 x0 = *(const float4*)ap0;
            float4 x1 = *(const float4*)(ap0 + 4);
            float4 y0 = *(const float4*)ap1;
            float4 y1 = *(const float4*)(ap1 + 4);
            af0[0] = (short)f2bf(x0.x); af0[1] = (short)f2bf(x0.y);
            af0[2] = (short)f2bf(x0.z); af0[3] = (short)f2bf(x0.w);
            af0[4] = (short)f2bf(x1.x); af0[5] = (short)f2bf(x1.y);
            af0[6] = (short)f2bf(x1.z); af0[7] = (short)f2bf(x1.w);
            af1[0] = (short)f2bf(y0.x); af1[1] = (short)f2bf(y0.y);
            af1[2] = (short)f2bf(y0.z); af1[3] = (short)f2bf(y0.w);
            af1[4] = (short)f2bf(y1.x); af1[5] = (short)f2bf(y1.y);
            af1[6] = (short)f2bf(y1.z); af1[7] = (short)f2bf(y1.w);
        } else {
            af0 = *(const short8*)(Ab + (size_t)rowA0 * 128 + k0);
            af1 = *(const short8*)(Ab + (size_t)rowA1 * 128 + k0);
        }
#pragma unroll
        for (int nt = 0; nt < NT; ++nt) {
            short8 bfr = *(const short8*)(Bs + ((size_t)(ks * NT + nt) * 64 + l) * 8);
            acc0[nt] = __builtin_amdgcn_mfma_f32_16x16x32_bf16(af0, bfr, acc0[nt], 0, 0, 0);
            acc1[nt] = __builtin_amdgcn_mfma_f32_16x16x32_bf16(af1, bfr, acc1[nt], 0, 0, 0);
        }
    }

    gemm_epilogue<MODE>(acc0, r0, lg, lc, bias, outB, alS, alD);
    if (has1) gemm_epilogue<MODE>(acc1, r0 + 16, lg, lc, bias, outB, alS, alD);
}

// ---------------------------------------------------------------------------
// Fused GAT aggregation (unchanged from round 7).
// ---------------------------------------------------------------------------
template <int H, int FINAL>
__launch_bounds__(256)
__global__ void gat_aggregate(const ushort_t* __restrict__ hWb,
                              const float* __restrict__ alS,
                              const float* __restrict__ alD,
                              const int* __restrict__ rowp,
                              const int* __restrict__ csrc,
                              const float* __restrict__ bias,
                              const ushort_t* __restrict__ resb,
                              ushort_t* __restrict__ outb,
                              float* __restrict__ outf, int n) {
    __shared__ float pbuf[4][64][4];
    __shared__ int obuf[4][64];
    int wid = threadIdx.x >> 6;
    int lane = threadIdx.x & 63;
    int node = blockIdx.x * 4 + wid;
    if (node >= n) return;
    int g = lane >> 4;
    int j = lane & 15;
    int hsel = (H == 4) ? (j >> 2) : 0;
    float ald[4];
    if (H == 4) {
        float4 t = *(const float4*)(alD + (size_t)node * 4);
        ald[0] = t.x; ald[1] = t.y; ald[2] = t.z; ald[3] = t.w;
    } else {
        ald[0] = alD[node];
    }
    int beg = rowp[node], end = rowp[node + 1];
    float zp0 = 0.f, zp1 = 0.f, zp2 = 0.f, zp3 = 0.f;
    float acc[8];
#pragma unroll
    for (int c = 0; c < 8; ++c) acc[c] = 0.f;
    const char* hbase = (const char*)hWb;
    int jo = j << 4;

    for (int base = beg; base < end; base += 64) {
        int nc = min(64, end - base);
        if (lane < nc) {
            int s = csrc[base + lane];
            obuf[wid][lane] = s << 8;
            if (H == 4) {
                float4 t = *(const float4*)(alS + (size_t)s * 4);
                float x0 = t.x + ald[0], x1 = t.y + ald[1];
                float x2 = t.z + ald[2], x3 = t.w + ald[3];
                x0 = (x0 > 0.f) ? x0 : 0.2f * x0;
                x1 = (x1 > 0.f) ? x1 : 0.2f * x1;
                x2 = (x2 > 0.f) ? x2 : 0.2f * x2;
                x3 = (x3 > 0.f) ? x3 : 0.2f * x3;
                float p0 = __expf(x0), p1 = __expf(x1);
                float p2 = __expf(x2), p3 = __expf(x3);
                zp0 += p0; zp1 += p1; zp2 += p2; zp3 += p3;
                float4 t4; t4.x = p0; t4.y = p1; t4.z = p2; t4.w = p3;
                *(float4*)&pbuf[wid][lane][0] = t4;
            } else {
                float x = alS[s] + ald[0];
                x = (x > 0.f) ? x : 0.2f * x;
                float p = __expf(x);
                zp0 += p;
                pbuf[wid][lane][0] = p;
            }
        } else {
            obuf[wid][lane] = node << 8;
            if (H == 4) {
                float4 t4; t4.x = 0.f; t4.y = 0.f; t4.z = 0.f; t4.w = 0.f;
                *(float4*)&pbuf[wid][lane][0] = t4;
            } else {
                pbuf[wid][lane][0] = 0.f;
            }
        }
        int padded = (nc + 7) & ~7;
        for (int i = 0; i < padded; i += 8) {
            int i0 = i + g, i1 = i + 4 + g;
            int o0 = obuf[wid][i0];
            int o1 = obuf[wid][i1];
            float p0 = pbuf[wid][i0][hsel];
            float p1 = pbuf[wid][i1][hsel];
            uint4 h0 = *(const uint4*)(hbase + o0 + jo);
            uint4 h1 = *(const uint4*)(hbase + o1 + jo);
            acc[0] += p0 * bf2f_lo(h0.x); acc[1] += p0 * bf2f_hi_fast(h0.x);
            acc[2] += p0 * bf2f_lo(h0.y); acc[3] += p0 * bf2f_hi_fast(h0.y);
            acc[4] += p0 * bf2f_lo(h0.z); acc[5] += p0 * bf2f_hi_fast(h0.z);
            acc[6] += p0 * bf2f_lo(h0.w); acc[7] += p0 * bf2f_hi_fast(h0.w);
            acc[0] += p1 * bf2f_lo(h1.x); acc[1] += p1 * bf2f_hi_fast(h1.x);
            acc[2] += p1 * bf2f_lo(h1.y); acc[3] += p1 * bf2f_hi_fast(h1.y);
            acc[4] += p1 * bf2f_lo(h1.z); acc[5] += p1 * bf2f_hi_fast(h1.z);
            acc[6] += p1 * bf2f_lo(h1.w); acc[7] += p1 * bf2f_hi_fast(h1.w);
        }
    }

#pragma unroll
    for (int c = 0; c < 8; ++c) {
        acc[c] += __shfl_xor(acc[c], 16, 64);
        acc[c] += __shfl_xor(acc[c], 32, 64);
    }
#pragma unroll
    for (int off = 1; off < 64; off <<= 1) {
        zp0 += __shfl_xor(zp0, off, 64);
        if (H == 4) {
            zp1 += __shfl_xor(zp1, off, 64);
            zp2 += __shfl_xor(zp2, off, 64);
            zp3 += __shfl_xor(zp3, off, 64);
        }
    }
    float zv;
    if (H == 1) zv = zp0;
    else zv = (hsel == 0) ? zp0 : (hsel == 1) ? zp1 : (hsel == 2) ? zp2 : zp3;
    float inv = 1.f / (zv + 1e-16f);

    int c0 = j * 8;
    const float4* bp = (const float4*)(bias + c0);
    float4 bv0 = bp[0], bv1 = bp[1];
    float val[8];
    val[0] = acc[0] * inv + bv0.x; val[1] = acc[1] * inv + bv0.y;
    val[2] = acc[2] * inv + bv0.z; val[3] = acc[3] * inv + bv0.w;
    val[4] = acc[4] * inv + bv1.x; val[5] = acc[5] * inv + bv1.y;
    val[6] = acc[6] * inv + bv1.z; val[7] = acc[7] * inv + bv1.w;
    if (!FINAL) {
        uint4 rv = *((const uint4*)(resb + ((size_t)node << 7)) + j);
        float rr[8] = {bf2f_lo(rv.x), bf2f_hi(rv.x), bf2f_lo(rv.y), bf2f_hi(rv.y),
                       bf2f_lo(rv.z), bf2f_hi(rv.z), bf2f_lo(rv.w), bf2f_hi(rv.w)};
#pragma unroll
        for (int c = 0; c < 8; ++c) {
            float vv = val[c];
            float ev = __expf(vv) - 1.f;
            val[c] = ((vv > 0.f) ? vv : ev) + rr[c];
        }
    }
    float s2 = 0.f;
#pragma unroll
    for (int c = 0; c < 8; ++c) s2 += val[c];
#pragma unroll
    for (int off = 1; off < 16; off <<= 1) s2 += __shfl_xor(s2, off, 64);
    float mean = s2 * (1.f / 128.f);
    float q = 0.f;
    float dd[8];
#pragma unroll
    for (int c = 0; c < 8; ++c) {
        dd[c] = val[c] - mean;
        q += dd[c] * dd[c];
    }
#pragma unroll
    for (int off = 1; off < 16; off <<= 1) q += __shfl_xor(q, off, 64);
    float r = rsqrtf(q * (1.f / 128.f) + 1e-5f);
    if (g == 0) {
        if (FINAL) {
            float* op = outf + ((size_t)node << 7) + c0;
            *(float4*)op = make_float4(dd[0] * r, dd[1] * r, dd[2] * r, dd[3] * r);
            *(float4*)(op + 4) = make_float4(dd[4] * r, dd[5] * r, dd[6] * r, dd[7] * r);
        } else {
            uint4 u;
            u.x = (uint_t)f2bf(dd[0] * r) | ((uint_t)f2bf(dd[1] * r) << 16);
            u.y = (uint_t)f2bf(dd[2] * r) | ((uint_t)f2bf(dd[3] * r) << 16);
            u.z = (uint_t)f2bf(dd[4] * r) | ((uint_t)f2bf(dd[5] * r) << 16);
            u.w = (uint_t)f2bf(dd[6] * r) | ((uint_t)f2bf(dd[7] * r) << 16);
            *((uint4*)(outb + ((size_t)node << 7)) + j) = u;
        }
    }
}

// ---------------------------------------------------------------------------
extern "C" void kernel_launch(void* const* d_in, const int* in_sizes, int n_in,
                              void* d_out, int out_size, void* d_ws, size_t ws_size,
                              hipStream_t stream) {
    const int N = in_sizes[0] / 128;
    const int E = in_sizes[1] / 2;
    const int Etot = E + N;
    const int NB = (N + BCK - 1) / BCK;
    const int NBLK = (Etot + EPB - 1) / EPB;

    const float* x    = (const float*)d_in[0];
    const int*   ei   = (const int*)d_in[1];
    const float* W_in = (const float*)d_in[2];
    const float* b_in = (const float*)d_in[3];
    const float* W0   = (const float*)d_in[4];
    const float* as0  = (const float*)d_in[5];
    const float* ad0  = (const float*)d_in[6];
    const float* b0   = (const float*)d_in[7];
    const float* W1   = (const float*)d_in[8];
    const float* as1  = (const float*)d_in[9];
    const float* ad1  = (const float*)d_in[10];
    const float* b1   = (const float*)d_in[11];
    const float* W2   = (const float*)d_in[12];
    const float* as2  = (const float*)d_in[13];
    const float* ad2  = (const float*)d_in[14];
    const float* b2   = (const float*)d_in[15];

    char* wsp = (char*)d_ws;
    size_t off = 0;
    auto carve = [&](size_t bytes) -> void* {
        void* p = wsp + off;
        off += (bytes + 255) & ~(size_t)255;
        return p;
    };
    ushort_t* hAb  = (ushort_t*)carve((size_t)N * 128 * 2);
    ushort_t* hBb  = (ushort_t*)carve((size_t)N * 128 * 2);
    ushort_t* hWb  = (ushort_t*)carve((size_t)N * 128 * 2);
    float*    alS  = (float*)carve((size_t)N * 4 * 4);
    float*    alD  = (float*)carve((size_t)N * 4 * 4);
    int*      rowp = (int*)carve((size_t)(N + 1) * 4);
    int*      csrc = (int*)carve((size_t)Etot * 4);
    int*      bhist= (int*)carve((size_t)NBLK * 256 * 4);
    int*      obase= (int*)carve((size_t)NBLK * 256 * 4);
    int*      gbase= (int*)carve((size_t)257 * 4);
    ushort_t* BfIn = (ushort_t*)carve((size_t)4 * 8 * 64 * 8 * 2);
    ushort_t* Bf0  = (ushort_t*)carve((size_t)4 * 9 * 64 * 8 * 2);
    ushort_t* Bf1  = (ushort_t*)carve((size_t)4 * 9 * 64 * 8 * 2);
    ushort_t* Bf2  = (ushort_t*)carve((size_t)4 * 9 * 64 * 8 * 2);
    // pairs aliases hWb: lifetime ends (bucket_csr) before hWb is written (gemm<1>)
    uint2*    pairs = (uint2*)hWb;
    (void)ws_size; (void)n_in; (void)out_size;

    // bfrag x4 + per-block histograms (atomic-free)
    prep_kernel<<<35 + NBLK, 256, 0, stream>>>(W_in, W0, as0, ad0, W1, as1, ad1,
                                               W2, as2, ad2, BfIn, Bf0, Bf1, Bf2,
                                               ei, bhist, E, N);
    csr_scan<<<1, 256, 0, stream>>>(bhist, obase, gbase, rowp, NBLK, N, Etot);
    csr_scatter<<<NBLK, 256, 0, stream>>>(ei, gbase, obase, pairs, E, N);
    bucket_csr<<<NB, 256, 0, stream>>>(pairs, gbase, rowp, csrc, N);

    int gg = (N + 127) / 128;
    int ga = (N + 3) / 4;

    // h = relu(x @ W_in + b_in) -> bf16
    gemm_mfma<0><<<gg, 256, 0, stream>>>(x, nullptr, BfIn, b_in, hAb,
                                         nullptr, nullptr, N);
    // Layer 0
    gemm_mfma<1><<<gg, 256, 0, stream>>>(nullptr, hAb, Bf0, nullptr, hWb, alS, alD, N);
    gat_aggregate<4, 0><<<ga, 256, 0, stream>>>(hWb, alS, alD, rowp, csrc, b0,
                                                hAb, hBb, nullptr, N);
    // Layer 1
    gemm_mfma<1><<<gg, 256, 0, stream>>>(nullptr, hBb, Bf1, nullptr, hWb, alS, alD, N);
    gat_aggregate<4, 0><<<ga, 256, 0, stream>>>(hWb, alS, alD, rowp, csrc, b1,
                                                hBb, hAb, nullptr, N);
    // Layer 2 (heads=1)
    gemm_mfma<2><<<gg, 256, 0, stream>>>(nullptr, hAb, Bf2, nullptr, hWb, alS, alD, N);
    gat_aggregate<1, 1><<<ga, 256, 0, stream>>>(hWb, alS, alD, rowp, csrc, b2,
                                                nullptr, nullptr, (float*)d_out, N);
}

// Round 9
// 229.625 us; speedup vs baseline: 1.1974x; 1.1974x over previous
//
#include <hip/hip_runtime.h>
#include <hip/hip_bf16.h>

typedef unsigned short ushort_t;
typedef unsigned int uint_t;
typedef __attribute__((ext_vector_type(8))) short short8;
typedef __attribute__((ext_vector_type(4))) float f32x4;

__device__ __forceinline__ ushort_t f2bf(float f) {
    uint_t u = __float_as_uint(f);
    uint_t r = (u + 0x7FFFu + ((u >> 16) & 1u)) >> 16;
    return (ushort_t)r;
}
__device__ __forceinline__ float bf2f_lo(uint_t u) { return __uint_as_float(u << 16); }
__device__ __forceinline__ float bf2f_hi(uint_t u) { return __uint_as_float(u & 0xffff0000u); }
// hi bf16 with low 16 bits left as extra-mantissa garbage (<=2^-9 relative).
__device__ __forceinline__ float bf2f_hi_fast(uint_t u) { return __uint_as_float(u); }

#define BSH 8
#define BCK 256
#define CSR_CAP 6144
#define EPB 4096   // edges per histogram/scatter block (NBLK <= 256)

// ---------------------------------------------------------------------------
// prep_kernel: blocks 0..34 build the 4 B-fragment tables (MFMA layout),
// blocks 35.. write per-block bucket histograms (NO global atomics).
// bhist layout: [blk][256].
// ---------------------------------------------------------------------------
__global__ void prep_kernel(const float* __restrict__ W_in,
                            const float* __restrict__ W0, const float* __restrict__ as0,
                            const float* __restrict__ ad0,
                            const float* __restrict__ W1, const float* __restrict__ as1,
                            const float* __restrict__ ad1,
                            const float* __restrict__ W2, const float* __restrict__ as2,
                            const float* __restrict__ ad2,
                            ushort_t* __restrict__ BfIn, ushort_t* __restrict__ Bf0,
                            ushort_t* __restrict__ Bf1, ushort_t* __restrict__ Bf2,
                            const int* __restrict__ ei, int* __restrict__ bhist,
                            int E, int N) {
    __shared__ int hist[256];
    int b = blockIdx.x;
    if (b < 35) {
        const float *W, *a_s, *a_d;
        ushort_t* Bf;
        int H, NT, nt;
        if (b < 8)       { W = W_in; a_s = nullptr; a_d = nullptr; Bf = BfIn; H = 0; NT = 8; nt = b; }
        else if (b < 17) { W = W0; a_s = as0; a_d = ad0; Bf = Bf0; H = 4; NT = 9; nt = b - 8; }
        else if (b < 26) { W = W1; a_s = as1; a_d = ad1; Bf = Bf1; H = 4; NT = 9; nt = b - 17; }
        else             { W = W2; a_s = as2; a_d = ad2; Bf = Bf2; H = 1; NT = 9; nt = b - 26; }
        int l = threadIdx.x & 63;
        int ks = threadIdx.x >> 6;
        int kb = ks * 32 + (l >> 4) * 8;
        int col = l & 15;
        ushort_t v[8];
        if (nt < 8) {
#pragma unroll
            for (int j = 0; j < 8; ++j)
                v[j] = f2bf(W[(size_t)(kb + j) * 128 + nt * 16 + col]);
        } else {
#pragma unroll
            for (int j = 0; j < 8; ++j) {
                int k = kb + j;
                float s = 0.f;
                if (H == 4) {
                    if (col < 4) {
                        for (int c = 0; c < 32; ++c)
                            s += W[(size_t)k * 128 + col * 32 + c] * a_s[col * 32 + c];
                    } else if (col < 8) {
                        int h = col - 4;
                        for (int c = 0; c < 32; ++c)
                            s += W[(size_t)k * 128 + h * 32 + c] * a_d[h * 32 + c];
                    }
                } else {
                    if (col == 0) {
                        for (int c = 0; c < 128; ++c) s += W[(size_t)k * 128 + c] * a_s[c];
                    } else if (col == 1) {
                        for (int c = 0; c < 128; ++c) s += W[(size_t)k * 128 + c] * a_d[c];
                    }
                }
                v[j] = f2bf(s);
            }
        }
        uint4 u;
        u.x = (uint_t)v[0] | ((uint_t)v[1] << 16);
        u.y = (uint_t)v[2] | ((uint_t)v[3] << 16);
        u.z = (uint_t)v[4] | ((uint_t)v[5] << 16);
        u.w = (uint_t)v[6] | ((uint_t)v[7] << 16);
        *(uint4*)(Bf + ((size_t)(ks * NT + nt) * 64 + l) * 8) = u;
    } else {
        int tid = threadIdx.x;
        int blk = b - 35;
        hist[tid] = 0;
        __syncthreads();
        int base = blk * EPB;
        int Etot = E + N;
#pragma unroll
        for (int r = 0; r < EPB / 256; ++r) {
            int i = base + r * 256 + tid;
            if (i < Etot) {
                int dst = (i < E) ? ei[E + i] : (i - E);
                atomicAdd(&hist[dst >> BSH], 1);
            }
        }
        __syncthreads();
        bhist[blk * 256 + tid] = hist[tid];
    }
}

// ---------------------------------------------------------------------------
// csr_scan1: block b owns bucket b. Exclusive scan of bhist[*][b] over blocks
// -> obase[blk][b]; bucket total -> gtot[b]. Fully parallel (256 blocks).
// ---------------------------------------------------------------------------
__global__ void csr_scan1(const int* __restrict__ bhist, int* __restrict__ obase,
                          int* __restrict__ gtot, int NBLK) {
    __shared__ int ws[4];
    int b = blockIdx.x;
    int t = threadIdx.x;
    int v = (t < NBLK) ? bhist[t * 256 + b] : 0;
    int lane = t & 63, w = t >> 6;
    int x = v;
#pragma unroll
    for (int off = 1; off < 64; off <<= 1) {
        int t2 = __shfl_up(x, off, 64);
        if (lane >= off) x += t2;
    }
    if (lane == 63) ws[w] = x;
    __syncthreads();
    int add = 0;
    for (int j = 0; j < w; ++j) add += ws[j];
    int excl = add + x - v;
    if (t < NBLK) obase[t * 256 + b] = excl;
    if (t == 255) gtot[b] = excl + v;
}

// csr_scan2: exclusive scan of the 256 bucket totals -> gbase.
__global__ void csr_scan2(const int* __restrict__ gtot, int* __restrict__ gbase,
                          int* __restrict__ rowp, int N, int Etot) {
    __shared__ int ws[4];
    int t = threadIdx.x;
    int v = gtot[t];
    int lane = t & 63, w = t >> 6;
    int x = v;
#pragma unroll
    for (int off = 1; off < 64; off <<= 1) {
        int t2 = __shfl_up(x, off, 64);
        if (lane >= off) x += t2;
    }
    if (lane == 63) ws[w] = x;
    __syncthreads();
    int add = 0;
    for (int j = 0; j < w; ++j) add += ws[j];
    gbase[t] = add + x - v;
    if (t == 0) {
        gbase[256] = Etot;
        rowp[N] = Etot;
    }
}

// ---------------------------------------------------------------------------
// csr_scatter: LDS-only atomics; global positions pre-assigned per block.
// ---------------------------------------------------------------------------
__global__ void csr_scatter(const int* __restrict__ ei, const int* __restrict__ gbase,
                            const int* __restrict__ obase, uint2* __restrict__ pairs,
                            int E, int N) {
    __shared__ int cur[256];
    int tid = threadIdx.x;
    int blk = blockIdx.x;
    cur[tid] = gbase[tid] + obase[blk * 256 + tid];
    __syncthreads();
    int base = blk * EPB;
    int Etot = E + N;
#pragma unroll
    for (int r = 0; r < EPB / 256; ++r) {
        int i = base + r * 256 + tid;
        if (i < Etot) {
            int src = (i < E) ? ei[i] : (i - E);
            int dst = (i < E) ? ei[E + i] : (i - E);
            int pos = atomicAdd(&cur[dst >> BSH], 1);
            uint2 p;
            p.x = (uint_t)src;
            p.y = (uint_t)dst;
            pairs[pos] = p;
        }
    }
}

__global__ void bucket_csr(const uint2* __restrict__ pairs, const int* __restrict__ gbase,
                           int* __restrict__ rowp, int* __restrict__ csrc, int N) {
    __shared__ int cnt[256];
    __shared__ int ws[4];
    __shared__ int stage[CSR_CAP];
    int b = blockIdx.x, tid = threadIdx.x;
    int eBeg = gbase[b], eEnd = gbase[b + 1];
    int M = eEnd - eBeg;
    cnt[tid] = 0;
    __syncthreads();
    for (int t = tid; t < M; t += 256) {
        uint2 pr = pairs[eBeg + t];
        atomicAdd(&cnt[pr.y & (BCK - 1)], 1);
    }
    __syncthreads();
    int v = cnt[tid];
    int lane = tid & 63, w = tid >> 6;
    int x = v;
#pragma unroll
    for (int off = 1; off < 64; off <<= 1) {
        int t2 = __shfl_up(x, off, 64);
        if (lane >= off) x += t2;
    }
    if (lane == 63) ws[w] = x;
    __syncthreads();
    int add = 0;
    for (int j = 0; j < w; ++j) add += ws[j];
    int excl = add + x - v;
    int node = (b << BSH) + tid;
    if (node < N) rowp[node] = eBeg + excl;
    __syncthreads();
    cnt[tid] = excl;
    __syncthreads();
    for (int t = tid; t < M; t += 256) {
        uint2 pr = pairs[eBeg + t];
        int pos = atomicAdd(&cnt[pr.y & (BCK - 1)], 1);
        if (pos < CSR_CAP) stage[pos] = (int)pr.x;
        else csrc[eBeg + pos] = (int)pr.x;
    }
    __syncthreads();
    int lim = (M < CSR_CAP) ? M : CSR_CAP;
    for (int t = tid; t < lim; t += 256) csrc[eBeg + t] = stage[t];
}

// ---------------------------------------------------------------------------
// MFMA GEMM: TWO 16-row tiles per wave; B staged in LDS per block.
// ---------------------------------------------------------------------------
template <int MODE>
__device__ __forceinline__ void gemm_epilogue(f32x4* acc, int r0, int lg, int lc,
                                              const float* bias, ushort_t* outB,
                                              float* alS, float* alD) {
    if (MODE == 0) {
#pragma unroll
        for (int r = 0; r < 4; ++r) {
            int row = r0 + lg * 4 + r;
            ushort_t* op = outB + (size_t)row * 128 + lc;
#pragma unroll
            for (int nt = 0; nt < 8; ++nt) {
                float v = fmaxf(acc[nt][r] + bias[nt * 16 + lc], 0.f);
                op[nt * 16] = f2bf(v);
            }
        }
    } else {
#pragma unroll
        for (int r = 0; r < 4; ++r) {
            int row = r0 + lg * 4 + r;
            ushort_t* op = outB + (size_t)row * 128 + lc;
#pragma unroll
            for (int nt = 0; nt < 8; ++nt) op[nt * 16] = f2bf(acc[nt][r]);
            float lv = acc[8][r];
            if (MODE == 1) {
                if (lc < 4) alS[(size_t)row * 4 + lc] = lv;
                else if (lc < 8) alD[(size_t)row * 4 + (lc - 4)] = lv;
            } else {
                if (lc == 0) alS[row] = lv;
                else if (lc == 1) alD[row] = lv;
            }
        }
    }
}

template <int MODE>
__launch_bounds__(256)
__global__ void gemm_mfma(const float* __restrict__ Af, const ushort_t* __restrict__ Ab,
                          const ushort_t* __restrict__ Bf, const float* __restrict__ bias,
                          ushort_t* __restrict__ outB, float* __restrict__ alS,
                          float* __restrict__ alD, int M) {
    const int NT = (MODE == 0) ? 8 : 9;
    __shared__ ushort_t Bs[4 * 9 * 64 * 8];
    {
        const int tot = 4 * NT * 64;
        for (int t = threadIdx.x; t < tot; t += 256)
            ((uint4*)Bs)[t] = ((const uint4*)Bf)[t];
    }
    __syncthreads();

    int wid = threadIdx.x >> 6, l = threadIdx.x & 63;
    int lg = l >> 4, lc = l & 15;
    int r0 = (blockIdx.x * 4 + wid) * 32;
    if (r0 >= M) return;
    bool has1 = (r0 + 16) < M;
    int rowA0 = r0 + lc;
    int rowA1 = has1 ? (r0 + 16 + lc) : rowA0;

    f32x4 acc0[9], acc1[9];
#pragma unroll
    for (int nt = 0; nt < NT; ++nt) {
        acc0[nt] = (f32x4){0.f, 0.f, 0.f, 0.f};
        acc1[nt] = (f32x4){0.f, 0.f, 0.f, 0.f};
    }

#pragma unroll
    for (int ks = 0; ks < 4; ++ks) {
        int k0 = ks * 32 + lg * 8;
        short8 af0, af1;
        if (MODE == 0) {
            const float* ap0 = Af + (size_t)rowA0 * 128 + k0;
            const float* ap1 = Af + (size_t)rowA1 * 128 + k0;
            float4 x0 = *(const float4*)ap0;
            float4 x1 = *(const float4*)(ap0 + 4);
            float4 y0 = *(const float4*)ap1;
            float4 y1 = *(const float4*)(ap1 + 4);
            af0[0] = (short)f2bf(x0.x); af0[1] = (short)f2bf(x0.y);
            af0[2] = (short)f2bf(x0.z); af0[3] = (short)f2bf(x0.w);
            af0[4] = (short)f2bf(x1.x); af0[5] = (short)f2bf(x1.y);
            af0[6] = (short)f2bf(x1.z); af0[7] = (short)f2bf(x1.w);
            af1[0] = (short)f2bf(y0.x); af1[1] = (short)f2bf(y0.y);
            af1[2] = (short)f2bf(y0.z); af1[3] = (short)f2bf(y0.w);
            af1[4] = (short)f2bf(y1.x); af1[5] = (short)f2bf(y1.y);
            af1[6] = (short)f2bf(y1.z); af1[7] = (short)f2bf(y1.w);
        } else {
            af0 = *(const short8*)(Ab + (size_t)rowA0 * 128 + k0);
            af1 = *(const short8*)(Ab + (size_t)rowA1 * 128 + k0);
        }
#pragma unroll
        for (int nt = 0; nt < NT; ++nt) {
            short8 bfr = *(const short8*)(Bs + ((size_t)(ks * NT + nt) * 64 + l) * 8);
            acc0[nt] = __builtin_amdgcn_mfma_f32_16x16x32_bf16(af0, bfr, acc0[nt], 0, 0, 0);
            acc1[nt] = __builtin_amdgcn_mfma_f32_16x16x32_bf16(af1, bfr, acc1[nt], 0, 0, 0);
        }
    }

    gemm_epilogue<MODE>(acc0, r0, lg, lc, bias, outB, alS, alD);
    if (has1) gemm_epilogue<MODE>(acc1, r0 + 16, lg, lc, bias, outB, alS, alD);
}

// ---------------------------------------------------------------------------
// Fused GAT aggregation (unchanged).
// ---------------------------------------------------------------------------
template <int H, int FINAL>
__launch_bounds__(256)
__global__ void gat_aggregate(const ushort_t* __restrict__ hWb,
                              const float* __restrict__ alS,
                              const float* __restrict__ alD,
                              const int* __restrict__ rowp,
                              const int* __restrict__ csrc,
                              const float* __restrict__ bias,
                              const ushort_t* __restrict__ resb,
                              ushort_t* __restrict__ outb,
                              float* __restrict__ outf, int n) {
    __shared__ float pbuf[4][64][4];
    __shared__ int obuf[4][64];
    int wid = threadIdx.x >> 6;
    int lane = threadIdx.x & 63;
    int node = blockIdx.x * 4 + wid;
    if (node >= n) return;
    int g = lane >> 4;
    int j = lane & 15;
    int hsel = (H == 4) ? (j >> 2) : 0;
    float ald[4];
    if (H == 4) {
        float4 t = *(const float4*)(alD + (size_t)node * 4);
        ald[0] = t.x; ald[1] = t.y; ald[2] = t.z; ald[3] = t.w;
    } else {
        ald[0] = alD[node];
    }
    int beg = rowp[node], end = rowp[node + 1];
    float zp0 = 0.f, zp1 = 0.f, zp2 = 0.f, zp3 = 0.f;
    float acc[8];
#pragma unroll
    for (int c = 0; c < 8; ++c) acc[c] = 0.f;
    const char* hbase = (const char*)hWb;
    int jo = j << 4;

    for (int base = beg; base < end; base += 64) {
        int nc = min(64, end - base);
        if (lane < nc) {
            int s = csrc[base + lane];
            obuf[wid][lane] = s << 8;
            if (H == 4) {
                float4 t = *(const float4*)(alS + (size_t)s * 4);
                float x0 = t.x + ald[0], x1 = t.y + ald[1];
                float x2 = t.z + ald[2], x3 = t.w + ald[3];
                x0 = (x0 > 0.f) ? x0 : 0.2f * x0;
                x1 = (x1 > 0.f) ? x1 : 0.2f * x1;
                x2 = (x2 > 0.f) ? x2 : 0.2f * x2;
                x3 = (x3 > 0.f) ? x3 : 0.2f * x3;
                float p0 = __expf(x0), p1 = __expf(x1);
                float p2 = __expf(x2), p3 = __expf(x3);
                zp0 += p0; zp1 += p1; zp2 += p2; zp3 += p3;
                float4 t4; t4.x = p0; t4.y = p1; t4.z = p2; t4.w = p3;
                *(float4*)&pbuf[wid][lane][0] = t4;
            } else {
                float x = alS[s] + ald[0];
                x = (x > 0.f) ? x : 0.2f * x;
                float p = __expf(x);
                zp0 += p;
                pbuf[wid][lane][0] = p;
            }
        } else {
            obuf[wid][lane] = node << 8;
            if (H == 4) {
                float4 t4; t4.x = 0.f; t4.y = 0.f; t4.z = 0.f; t4.w = 0.f;
                *(float4*)&pbuf[wid][lane][0] = t4;
            } else {
                pbuf[wid][lane][0] = 0.f;
            }
        }
        int padded = (nc + 7) & ~7;
        for (int i = 0; i < padded; i += 8) {
            int i0 = i + g, i1 = i + 4 + g;
            int o0 = obuf[wid][i0];
            int o1 = obuf[wid][i1];
            float p0 = pbuf[wid][i0][hsel];
            float p1 = pbuf[wid][i1][hsel];
            uint4 h0 = *(const uint4*)(hbase + o0 + jo);
            uint4 h1 = *(const uint4*)(hbase + o1 + jo);
            acc[0] += p0 * bf2f_lo(h0.x); acc[1] += p0 * bf2f_hi_fast(h0.x);
            acc[2] += p0 * bf2f_lo(h0.y); acc[3] += p0 * bf2f_hi_fast(h0.y);
            acc[4] += p0 * bf2f_lo(h0.z); acc[5] += p0 * bf2f_hi_fast(h0.z);
            acc[6] += p0 * bf2f_lo(h0.w); acc[7] += p0 * bf2f_hi_fast(h0.w);
            acc[0] += p1 * bf2f_lo(h1.x); acc[1] += p1 * bf2f_hi_fast(h1.x);
            acc[2] += p1 * bf2f_lo(h1.y); acc[3] += p1 * bf2f_hi_fast(h1.y);
            acc[4] += p1 * bf2f_lo(h1.z); acc[5] += p1 * bf2f_hi_fast(h1.z);
            acc[6] += p1 * bf2f_lo(h1.w); acc[7] += p1 * bf2f_hi_fast(h1.w);
        }
    }

#pragma unroll
    for (int c = 0; c < 8; ++c) {
        acc[c] += __shfl_xor(acc[c], 16, 64);
        acc[c] += __shfl_xor(acc[c], 32, 64);
    }
#pragma unroll
    for (int off = 1; off < 64; off <<= 1) {
        zp0 += __shfl_xor(zp0, off, 64);
        if (H == 4) {
            zp1 += __shfl_xor(zp1, off, 64);
            zp2 += __shfl_xor(zp2, off, 64);
            zp3 += __shfl_xor(zp3, off, 64);
        }
    }
    float zv;
    if (H == 1) zv = zp0;
    else zv = (hsel == 0) ? zp0 : (hsel == 1) ? zp1 : (hsel == 2) ? zp2 : zp3;
    float inv = 1.f / (zv + 1e-16f);

    int c0 = j * 8;
    const float4* bp = (const float4*)(bias + c0);
    float4 bv0 = bp[0], bv1 = bp[1];
    float val[8];
    val[0] = acc[0] * inv + bv0.x; val[1] = acc[1] * inv + bv0.y;
    val[2] = acc[2] * inv + bv0.z; val[3] = acc[3] * inv + bv0.w;
    val[4] = acc[4] * inv + bv1.x; val[5] = acc[5] * inv + bv1.y;
    val[6] = acc[6] * inv + bv1.z; val[7] = acc[7] * inv + bv1.w;
    if (!FINAL) {
        uint4 rv = *((const uint4*)(resb + ((size_t)node << 7)) + j);
        float rr[8] = {bf2f_lo(rv.x), bf2f_hi(rv.x), bf2f_lo(rv.y), bf2f_hi(rv.y),
                       bf2f_lo(rv.z), bf2f_hi(rv.z), bf2f_lo(rv.w), bf2f_hi(rv.w)};
#pragma unroll
        for (int c = 0; c < 8; ++c) {
            float vv = val[c];
            float ev = __expf(vv) - 1.f;
            val[c] = ((vv > 0.f) ? vv : ev) + rr[c];
        }
    }
    float s2 = 0.f;
#pragma unroll
    for (int c = 0; c < 8; ++c) s2 += val[c];
#pragma unroll
    for (int off = 1; off < 16; off <<= 1) s2 += __shfl_xor(s2, off, 64);
    float mean = s2 * (1.f / 128.f);
    float q = 0.f;
    float dd[8];
#pragma unroll
    for (int c = 0; c < 8; ++c) {
        dd[c] = val[c] - mean;
        q += dd[c] * dd[c];
    }
#pragma unroll
    for (int off = 1; off < 16; off <<= 1) q += __shfl_xor(q, off, 64);
    float r = rsqrtf(q * (1.f / 128.f) + 1e-5f);
    if (g == 0) {
        if (FINAL) {
            float* op = outf + ((size_t)node << 7) + c0;
            *(float4*)op = make_float4(dd[0] * r, dd[1] * r, dd[2] * r, dd[3] * r);
            *(float4*)(op + 4) = make_float4(dd[4] * r, dd[5] * r, dd[6] * r, dd[7] * r);
        } else {
            uint4 u;
            u.x = (uint_t)f2bf(dd[0] * r) | ((uint_t)f2bf(dd[1] * r) << 16);
            u.y = (uint_t)f2bf(dd[2] * r) | ((uint_t)f2bf(dd[3] * r) << 16);
            u.z = (uint_t)f2bf(dd[4] * r) | ((uint_t)f2bf(dd[5] * r) << 16);
            u.w = (uint_t)f2bf(dd[6] * r) | ((uint_t)f2bf(dd[7] * r) << 16);
            *((uint4*)(outb + ((size_t)node << 7)) + j) = u;
        }
    }
}

// ---------------------------------------------------------------------------
extern "C" void kernel_launch(void* const* d_in, const int* in_sizes, int n_in,
                              void* d_out, int out_size, void* d_ws, size_t ws_size,
                              hipStream_t stream) {
    const int N = in_sizes[0] / 128;
    const int E = in_sizes[1] / 2;
    const int Etot = E + N;
    const int NB = (N + BCK - 1) / BCK;
    const int NBLK = (Etot + EPB - 1) / EPB;

    const float* x    = (const float*)d_in[0];
    const int*   ei   = (const int*)d_in[1];
    const float* W_in = (const float*)d_in[2];
    const float* b_in = (const float*)d_in[3];
    const float* W0   = (const float*)d_in[4];
    const float* as0  = (const float*)d_in[5];
    const float* ad0  = (const float*)d_in[6];
    const float* b0   = (const float*)d_in[7];
    const float* W1   = (const float*)d_in[8];
    const float* as1  = (const float*)d_in[9];
    const float* ad1  = (const float*)d_in[10];
    const float* b1   = (const float*)d_in[11];
    const float* W2   = (const float*)d_in[12];
    const float* as2  = (const float*)d_in[13];
    const float* ad2  = (const float*)d_in[14];
    const float* b2   = (const float*)d_in[15];

    char* wsp = (char*)d_ws;
    size_t off = 0;
    auto carve = [&](size_t bytes) -> void* {
        void* p = wsp + off;
        off += (bytes + 255) & ~(size_t)255;
        return p;
    };
    ushort_t* hAb  = (ushort_t*)carve((size_t)N * 128 * 2);
    ushort_t* hBb  = (ushort_t*)carve((size_t)N * 128 * 2);
    ushort_t* hWb  = (ushort_t*)carve((size_t)N * 128 * 2);
    float*    alS  = (float*)carve((size_t)N * 4 * 4);
    float*    alD  = (float*)carve((size_t)N * 4 * 4);
    int*      rowp = (int*)carve((size_t)(N + 1) * 4);
    int*      csrc = (int*)carve((size_t)Etot * 4);
    int*      bhist= (int*)carve((size_t)NBLK * 256 * 4);
    int*      obase= (int*)carve((size_t)NBLK * 256 * 4);
    int*      gbase= (int*)carve((size_t)257 * 4);
    int*      gtot = (int*)carve((size_t)256 * 4);
    ushort_t* BfIn = (ushort_t*)carve((size_t)4 * 8 * 64 * 8 * 2);
    ushort_t* Bf0  = (ushort_t*)carve((size_t)4 * 9 * 64 * 8 * 2);
    ushort_t* Bf1  = (ushort_t*)carve((size_t)4 * 9 * 64 * 8 * 2);
    ushort_t* Bf2  = (ushort_t*)carve((size_t)4 * 9 * 64 * 8 * 2);
    // pairs aliases hWb: lifetime ends (bucket_csr) before hWb is written (gemm<1>)
    uint2*    pairs = (uint2*)hWb;
    (void)ws_size; (void)n_in; (void)out_size;

    // bfrag x4 + per-block histograms (atomic-free)
    prep_kernel<<<35 + NBLK, 256, 0, stream>>>(W_in, W0, as0, ad0, W1, as1, ad1,
                                               W2, as2, ad2, BfIn, Bf0, Bf1, Bf2,
                                               ei, bhist, E, N);
    csr_scan1<<<256, 256, 0, stream>>>(bhist, obase, gtot, NBLK);
    csr_scan2<<<1, 256, 0, stream>>>(gtot, gbase, rowp, N, Etot);
    csr_scatter<<<NBLK, 256, 0, stream>>>(ei, gbase, obase, pairs, E, N);
    bucket_csr<<<NB, 256, 0, stream>>>(pairs, gbase, rowp, csrc, N);

    int gg = (N + 127) / 128;
    int ga = (N + 3) / 4;

    // h = relu(x @ W_in + b_in) -> bf16
    gemm_mfma<0><<<gg, 256, 0, stream>>>(x, nullptr, BfIn, b_in, hAb,
                                         nullptr, nullptr, N);
    // Layer 0
    gemm_mfma<1><<<gg, 256, 0, stream>>>(nullptr, hAb, Bf0, nullptr, hWb, alS, alD, N);
    gat_aggregate<4, 0><<<ga, 256, 0, stream>>>(hWb, alS, alD, rowp, csrc, b0,
                                                hAb, hBb, nullptr, N);
    // Layer 1
    gemm_mfma<1><<<gg, 256, 0, stream>>>(nullptr, hBb, Bf1, nullptr, hWb, alS, alD, N);
    gat_aggregate<4, 0><<<ga, 256, 0, stream>>>(hWb, alS, alD, rowp, csrc, b1,
                                                hBb, hAb, nullptr, N);
    // Layer 2 (heads=1)
    gemm_mfma<2><<<gg, 256, 0, stream>>>(nullptr, hAb, Bf2, nullptr, hWb, alS, alD, N);
    gat_aggregate<1, 1><<<ga, 256, 0, stream>>>(hWb, alS, alD, rowp, csrc, b2,
                                                nullptr, nullptr, (float*)d_out, N);
}

// Round 10
// 224.873 us; speedup vs baseline: 1.2227x; 1.0211x over previous
//
#include <hip/hip_runtime.h>
#include <hip/hip_bf16.h>

typedef unsigned short ushort_t;
typedef unsigned int uint_t;
typedef __attribute__((ext_vector_type(8))) short short8;
typedef __attribute__((ext_vector_type(4))) float f32x4;
typedef __attribute__((ext_vector_type(2))) float f32x2;

__device__ __forceinline__ ushort_t f2bf(float f) {
    uint_t u = __float_as_uint(f);
    uint_t r = (u + 0x7FFFu + ((u >> 16) & 1u)) >> 16;
    return (ushort_t)r;
}
__device__ __forceinline__ float bf2f_lo(uint_t u) { return __uint_as_float(u << 16); }
__device__ __forceinline__ float bf2f_hi(uint_t u) { return __uint_as_float(u & 0xffff0000u); }
// pair {lo bf16, hi bf16(+mantissa garbage <=2^-9 rel)} as packed f32x2
__device__ __forceinline__ f32x2 bf2x2(uint_t u) {
    f32x2 r;
    r.x = __uint_as_float(u << 16);
    r.y = __uint_as_float(u);
    return r;
}
// d = a*b + c on both lanes-halves in ONE VALU instruction (VOP3P).
__device__ __forceinline__ f32x2 pk_fma(f32x2 a, f32x2 b, f32x2 c) {
    f32x2 d;
    asm("v_pk_fma_f32 %0, %1, %2, %3" : "=v"(d) : "v"(a), "v"(b), "v"(c));
    return d;
}

#define BSH 8
#define BCK 256
#define CSR_CAP 6144
#define EPB 4096   // edges per histogram/scatter block (NBLK <= 256)

// ---------------------------------------------------------------------------
// prep_kernel: blocks 0..34 build the 4 B-fragment tables (MFMA layout),
// blocks 35.. write per-block bucket histograms (NO global atomics).
// ---------------------------------------------------------------------------
__global__ void prep_kernel(const float* __restrict__ W_in,
                            const float* __restrict__ W0, const float* __restrict__ as0,
                            const float* __restrict__ ad0,
                            const float* __restrict__ W1, const float* __restrict__ as1,
                            const float* __restrict__ ad1,
                            const float* __restrict__ W2, const float* __restrict__ as2,
                            const float* __restrict__ ad2,
                            ushort_t* __restrict__ BfIn, ushort_t* __restrict__ Bf0,
                            ushort_t* __restrict__ Bf1, ushort_t* __restrict__ Bf2,
                            const int* __restrict__ ei, int* __restrict__ bhist,
                            int E, int N) {
    __shared__ int hist[256];
    int b = blockIdx.x;
    if (b < 35) {
        const float *W, *a_s, *a_d;
        ushort_t* Bf;
        int H, NT, nt;
        if (b < 8)       { W = W_in; a_s = nullptr; a_d = nullptr; Bf = BfIn; H = 0; NT = 8; nt = b; }
        else if (b < 17) { W = W0; a_s = as0; a_d = ad0; Bf = Bf0; H = 4; NT = 9; nt = b - 8; }
        else if (b < 26) { W = W1; a_s = as1; a_d = ad1; Bf = Bf1; H = 4; NT = 9; nt = b - 17; }
        else             { W = W2; a_s = as2; a_d = ad2; Bf = Bf2; H = 1; NT = 9; nt = b - 26; }
        int l = threadIdx.x & 63;
        int ks = threadIdx.x >> 6;
        int kb = ks * 32 + (l >> 4) * 8;
        int col = l & 15;
        ushort_t v[8];
        if (nt < 8) {
#pragma unroll
            for (int j = 0; j < 8; ++j)
                v[j] = f2bf(W[(size_t)(kb + j) * 128 + nt * 16 + col]);
        } else {
#pragma unroll
            for (int j = 0; j < 8; ++j) {
                int k = kb + j;
                float s = 0.f;
                if (H == 4) {
                    if (col < 4) {
                        for (int c = 0; c < 32; ++c)
                            s += W[(size_t)k * 128 + col * 32 + c] * a_s[col * 32 + c];
                    } else if (col < 8) {
                        int h = col - 4;
                        for (int c = 0; c < 32; ++c)
                            s += W[(size_t)k * 128 + h * 32 + c] * a_d[h * 32 + c];
                    }
                } else {
                    if (col == 0) {
                        for (int c = 0; c < 128; ++c) s += W[(size_t)k * 128 + c] * a_s[c];
                    } else if (col == 1) {
                        for (int c = 0; c < 128; ++c) s += W[(size_t)k * 128 + c] * a_d[c];
                    }
                }
                v[j] = f2bf(s);
            }
        }
        uint4 u;
        u.x = (uint_t)v[0] | ((uint_t)v[1] << 16);
        u.y = (uint_t)v[2] | ((uint_t)v[3] << 16);
        u.z = (uint_t)v[4] | ((uint_t)v[5] << 16);
        u.w = (uint_t)v[6] | ((uint_t)v[7] << 16);
        *(uint4*)(Bf + ((size_t)(ks * NT + nt) * 64 + l) * 8) = u;
    } else {
        int tid = threadIdx.x;
        int blk = b - 35;
        hist[tid] = 0;
        __syncthreads();
        int base = blk * EPB;
        int Etot = E + N;
#pragma unroll
        for (int r = 0; r < EPB / 256; ++r) {
            int i = base + r * 256 + tid;
            if (i < Etot) {
                int dst = (i < E) ? ei[E + i] : (i - E);
                atomicAdd(&hist[dst >> BSH], 1);
            }
        }
        __syncthreads();
        bhist[blk * 256 + tid] = hist[tid];
    }
}

// ---------------------------------------------------------------------------
// csr_scan1: block b owns bucket b; exclusive scan over blocks.
// ---------------------------------------------------------------------------
__global__ void csr_scan1(const int* __restrict__ bhist, int* __restrict__ obase,
                          int* __restrict__ gtot, int NBLK) {
    __shared__ int ws[4];
    int b = blockIdx.x;
    int t = threadIdx.x;
    int v = (t < NBLK) ? bhist[t * 256 + b] : 0;
    int lane = t & 63, w = t >> 6;
    int x = v;
#pragma unroll
    for (int off = 1; off < 64; off <<= 1) {
        int t2 = __shfl_up(x, off, 64);
        if (lane >= off) x += t2;
    }
    if (lane == 63) ws[w] = x;
    __syncthreads();
    int add = 0;
    for (int j = 0; j < w; ++j) add += ws[j];
    int excl = add + x - v;
    if (t < NBLK) obase[t * 256 + b] = excl;
    if (t == 255) gtot[b] = excl + v;
}

// csr_scan2: exclusive scan of the 256 bucket totals -> gbase.
__global__ void csr_scan2(const int* __restrict__ gtot, int* __restrict__ gbase,
                          int* __restrict__ rowp, int N, int Etot) {
    __shared__ int ws[4];
    int t = threadIdx.x;
    int v = gtot[t];
    int lane = t & 63, w = t >> 6;
    int x = v;
#pragma unroll
    for (int off = 1; off < 64; off <<= 1) {
        int t2 = __shfl_up(x, off, 64);
        if (lane >= off) x += t2;
    }
    if (lane == 63) ws[w] = x;
    __syncthreads();
    int add = 0;
    for (int j = 0; j < w; ++j) add += ws[j];
    gbase[t] = add + x - v;
    if (t == 0) {
        gbase[256] = Etot;
        rowp[N] = Etot;
    }
}

// ---------------------------------------------------------------------------
// csr_scatter: LDS-only atomics; global positions pre-assigned per block.
// ---------------------------------------------------------------------------
__global__ void csr_scatter(const int* __restrict__ ei, const int* __restrict__ gbase,
                            const int* __restrict__ obase, uint2* __restrict__ pairs,
                            int E, int N) {
    __shared__ int cur[256];
    int tid = threadIdx.x;
    int blk = blockIdx.x;
    cur[tid] = gbase[tid] + obase[blk * 256 + tid];
    __syncthreads();
    int base = blk * EPB;
    int Etot = E + N;
#pragma unroll
    for (int r = 0; r < EPB / 256; ++r) {
        int i = base + r * 256 + tid;
        if (i < Etot) {
            int src = (i < E) ? ei[i] : (i - E);
            int dst = (i < E) ? ei[E + i] : (i - E);
            int pos = atomicAdd(&cur[dst >> BSH], 1);
            uint2 p;
            p.x = (uint_t)src;
            p.y = (uint_t)dst;
            pairs[pos] = p;
        }
    }
}

__global__ void bucket_csr(const uint2* __restrict__ pairs, const int* __restrict__ gbase,
                           int* __restrict__ rowp, int* __restrict__ csrc, int N) {
    __shared__ int cnt[256];
    __shared__ int ws[4];
    __shared__ int stage[CSR_CAP];
    int b = blockIdx.x, tid = threadIdx.x;
    int eBeg = gbase[b], eEnd = gbase[b + 1];
    int M = eEnd - eBeg;
    cnt[tid] = 0;
    __syncthreads();
    for (int t = tid; t < M; t += 256) {
        uint2 pr = pairs[eBeg + t];
        atomicAdd(&cnt[pr.y & (BCK - 1)], 1);
    }
    __syncthreads();
    int v = cnt[tid];
    int lane = tid & 63, w = tid >> 6;
    int x = v;
#pragma unroll
    for (int off = 1; off < 64; off <<= 1) {
        int t2 = __shfl_up(x, off, 64);
        if (lane >= off) x += t2;
    }
    if (lane == 63) ws[w] = x;
    __syncthreads();
    int add = 0;
    for (int j = 0; j < w; ++j) add += ws[j];
    int excl = add + x - v;
    int node = (b << BSH) + tid;
    if (node < N) rowp[node] = eBeg + excl;
    __syncthreads();
    cnt[tid] = excl;
    __syncthreads();
    for (int t = tid; t < M; t += 256) {
        uint2 pr = pairs[eBeg + t];
        int pos = atomicAdd(&cnt[pr.y & (BCK - 1)], 1);
        if (pos < CSR_CAP) stage[pos] = (int)pr.x;
        else csrc[eBeg + pos] = (int)pr.x;
    }
    __syncthreads();
    int lim = (M < CSR_CAP) ? M : CSR_CAP;
    for (int t = tid; t < lim; t += 256) csrc[eBeg + t] = stage[t];
}

// ---------------------------------------------------------------------------
// MFMA GEMM: TWO 16-row tiles per wave; B staged in LDS per block.
// ---------------------------------------------------------------------------
template <int MODE>
__device__ __forceinline__ void gemm_epilogue(f32x4* acc, int r0, int lg, int lc,
                                              const float* bias, ushort_t* outB,
                                              float* alS, float* alD) {
    if (MODE == 0) {
#pragma unroll
        for (int r = 0; r < 4; ++r) {
            int row = r0 + lg * 4 + r;
            ushort_t* op = outB + (size_t)row * 128 + lc;
#pragma unroll
            for (int nt = 0; nt < 8; ++nt) {
                float v = fmaxf(acc[nt][r] + bias[nt * 16 + lc], 0.f);
                op[nt * 16] = f2bf(v);
            }
        }
    } else {
#pragma unroll
        for (int r = 0; r < 4; ++r) {
            int row = r0 + lg * 4 + r;
            ushort_t* op = outB + (size_t)row * 128 + lc;
#pragma unroll
            for (int nt = 0; nt < 8; ++nt) op[nt * 16] = f2bf(acc[nt][r]);
            float lv = acc[8][r];
            if (MODE == 1) {
                if (lc < 4) alS[(size_t)row * 4 + lc] = lv;
                else if (lc < 8) alD[(size_t)row * 4 + (lc - 4)] = lv;
            } else {
                if (lc == 0) alS[row] = lv;
                else if (lc == 1) alD[row] = lv;
            }
        }
    }
}

template <int MODE>
__launch_bounds__(256)
__global__ void gemm_mfma(const float* __restrict__ Af, const ushort_t* __restrict__ Ab,
                          const ushort_t* __restrict__ Bf, const float* __restrict__ bias,
                          ushort_t* __restrict__ outB, float* __restrict__ alS,
                          float* __restrict__ alD, int M) {
    const int NT = (MODE == 0) ? 8 : 9;
    __shared__ ushort_t Bs[4 * 9 * 64 * 8];
    {
        const int tot = 4 * NT * 64;
        for (int t = threadIdx.x; t < tot; t += 256)
            ((uint4*)Bs)[t] = ((const uint4*)Bf)[t];
    }
    __syncthreads();

    int wid = threadIdx.x >> 6, l = threadIdx.x & 63;
    int lg = l >> 4, lc = l & 15;
    int r0 = (blockIdx.x * 4 + wid) * 32;
    if (r0 >= M) return;
    bool has1 = (r0 + 16) < M;
    int rowA0 = r0 + lc;
    int rowA1 = has1 ? (r0 + 16 + lc) : rowA0;

    f32x4 acc0[9], acc1[9];
#pragma unroll
    for (int nt = 0; nt < NT; ++nt) {
        acc0[nt] = (f32x4){0.f, 0.f, 0.f, 0.f};
        acc1[nt] = (f32x4){0.f, 0.f, 0.f, 0.f};
    }

#pragma unroll
    for (int ks = 0; ks < 4; ++ks) {
        int k0 = ks * 32 + lg * 8;
        short8 af0, af1;
        if (MODE == 0) {
            const float* ap0 = Af + (size_t)rowA0 * 128 + k0;
            const float* ap1 = Af + (size_t)rowA1 * 128 + k0;
            float4 x0 = *(const float4*)ap0;
            float4 x1 = *(const float4*)(ap0 + 4);
            float4 y0 = *(const float4*)ap1;
            float4 y1 = *(const float4*)(ap1 + 4);
            af0[0] = (short)f2bf(x0.x); af0[1] = (short)f2bf(x0.y);
            af0[2] = (short)f2bf(x0.z); af0[3] = (short)f2bf(x0.w);
            af0[4] = (short)f2bf(x1.x); af0[5] = (short)f2bf(x1.y);
            af0[6] = (short)f2bf(x1.z); af0[7] = (short)f2bf(x1.w);
            af1[0] = (short)f2bf(y0.x); af1[1] = (short)f2bf(y0.y);
            af1[2] = (short)f2bf(y0.z); af1[3] = (short)f2bf(y0.w);
            af1[4] = (short)f2bf(y1.x); af1[5] = (short)f2bf(y1.y);
            af1[6] = (short)f2bf(y1.z); af1[7] = (short)f2bf(y1.w);
        } else {
            af0 = *(const short8*)(Ab + (size_t)rowA0 * 128 + k0);
            af1 = *(const short8*)(Ab + (size_t)rowA1 * 128 + k0);
        }
#pragma unroll
        for (int nt = 0; nt < NT; ++nt) {
            short8 bfr = *(const short8*)(Bs + ((size_t)(ks * NT + nt) * 64 + l) * 8);
            acc0[nt] = __builtin_amdgcn_mfma_f32_16x16x32_bf16(af0, bfr, acc0[nt], 0, 0, 0);
            acc1[nt] = __builtin_amdgcn_mfma_f32_16x16x32_bf16(af1, bfr, acc1[nt], 0, 0, 0);
        }
    }

    gemm_epilogue<MODE>(acc0, r0, lg, lc, bias, outB, alS, alD);
    if (has1) gemm_epilogue<MODE>(acc1, r0 + 16, lg, lc, bias, outB, alS, alD);
}

// ---------------------------------------------------------------------------
// Fused GAT aggregation.
// Phase 1: lanes own edges; p per head -> pbuf (no z accumulation).
// Phase 2: 16-lane groups gather edges' rows as uint4, v_pk_fma_f32 pairs;
//          z accumulated per-lane in-loop (pz), combined with the same
//          shfl_xor(16,32) as the feature accumulators -> z[hsel(j)] free.
// ---------------------------------------------------------------------------
template <int H, int FINAL>
__launch_bounds__(256)
__global__ void gat_aggregate(const ushort_t* __restrict__ hWb,
                              const float* __restrict__ alS,
                              const float* __restrict__ alD,
                              const int* __restrict__ rowp,
                              const int* __restrict__ csrc,
                              const float* __restrict__ bias,
                              const ushort_t* __restrict__ resb,
                              ushort_t* __restrict__ outb,
                              float* __restrict__ outf, int n) {
    __shared__ float pbuf[4][64][4];
    __shared__ int obuf[4][64];
    int wid = threadIdx.x >> 6;
    int lane = threadIdx.x & 63;
    int node = blockIdx.x * 4 + wid;
    if (node >= n) return;
    int g = lane >> 4;
    int j = lane & 15;
    int hsel = (H == 4) ? (j >> 2) : 0;
    float ald[4];
    if (H == 4) {
        float4 t = *(const float4*)(alD + (size_t)node * 4);
        ald[0] = t.x; ald[1] = t.y; ald[2] = t.z; ald[3] = t.w;
    } else {
        ald[0] = alD[node];
    }
    int beg = rowp[node], end = rowp[node + 1];
    f32x2 acc2[4];
#pragma unroll
    for (int c = 0; c < 4; ++c) acc2[c] = (f32x2){0.f, 0.f};
    float pz = 0.f;
    const char* hbase = (const char*)hWb;
    int jo = j << 4;

    for (int base = beg; base < end; base += 64) {
        int nc = min(64, end - base);
        if (lane < nc) {
            int s = csrc[base + lane];
            obuf[wid][lane] = s << 8;
            if (H == 4) {
                float4 t = *(const float4*)(alS + (size_t)s * 4);
                float x0 = t.x + ald[0], x1 = t.y + ald[1];
                float x2 = t.z + ald[2], x3 = t.w + ald[3];
                x0 = (x0 > 0.f) ? x0 : 0.2f * x0;
                x1 = (x1 > 0.f) ? x1 : 0.2f * x1;
                x2 = (x2 > 0.f) ? x2 : 0.2f * x2;
                x3 = (x3 > 0.f) ? x3 : 0.2f * x3;
                float4 t4;
                t4.x = __expf(x0); t4.y = __expf(x1);
                t4.z = __expf(x2); t4.w = __expf(x3);
                *(float4*)&pbuf[wid][lane][0] = t4;
            } else {
                float x = alS[s] + ald[0];
                x = (x > 0.f) ? x : 0.2f * x;
                pbuf[wid][lane][0] = __expf(x);
            }
        } else {
            obuf[wid][lane] = node << 8;
            if (H == 4) {
                float4 t4; t4.x = 0.f; t4.y = 0.f; t4.z = 0.f; t4.w = 0.f;
                *(float4*)&pbuf[wid][lane][0] = t4;
            } else {
                pbuf[wid][lane][0] = 0.f;
            }
        }
        int padded = (nc + 7) & ~7;
        for (int i = 0; i < padded; i += 8) {
            int i0 = i + g, i1 = i + 4 + g;
            int o0 = obuf[wid][i0];
            int o1 = obuf[wid][i1];
            float p0 = pbuf[wid][i0][hsel];
            float p1 = pbuf[wid][i1][hsel];
            uint4 h0 = *(const uint4*)(hbase + o0 + jo);
            uint4 h1 = *(const uint4*)(hbase + o1 + jo);
            f32x2 pv0; pv0.x = p0; pv0.y = p0;
            f32x2 pv1; pv1.x = p1; pv1.y = p1;
            acc2[0] = pk_fma(bf2x2(h0.x), pv0, acc2[0]);
            acc2[1] = pk_fma(bf2x2(h0.y), pv0, acc2[1]);
            acc2[2] = pk_fma(bf2x2(h0.z), pv0, acc2[2]);
            acc2[3] = pk_fma(bf2x2(h0.w), pv0, acc2[3]);
            acc2[0] = pk_fma(bf2x2(h1.x), pv1, acc2[0]);
            acc2[1] = pk_fma(bf2x2(h1.y), pv1, acc2[1]);
            acc2[2] = pk_fma(bf2x2(h1.z), pv1, acc2[2]);
            acc2[3] = pk_fma(bf2x2(h1.w), pv1, acc2[3]);
            pz += p0 + p1;
        }
    }

    float acc[8] = {acc2[0].x, acc2[0].y, acc2[1].x, acc2[1].y,
                    acc2[2].x, acc2[2].y, acc2[3].x, acc2[3].y};
    // combine the 4 edge-groups; same reduction gives z for this j's head
#pragma unroll
    for (int c = 0; c < 8; ++c) {
        acc[c] += __shfl_xor(acc[c], 16, 64);
        acc[c] += __shfl_xor(acc[c], 32, 64);
    }
    pz += __shfl_xor(pz, 16, 64);
    pz += __shfl_xor(pz, 32, 64);
    float inv = 1.f / (pz + 1e-16f);

    int c0 = j * 8;
    const float4* bp = (const float4*)(bias + c0);
    float4 bv0 = bp[0], bv1 = bp[1];
    float val[8];
    val[0] = acc[0] * inv + bv0.x; val[1] = acc[1] * inv + bv0.y;
    val[2] = acc[2] * inv + bv0.z; val[3] = acc[3] * inv + bv0.w;
    val[4] = acc[4] * inv + bv1.x; val[5] = acc[5] * inv + bv1.y;
    val[6] = acc[6] * inv + bv1.z; val[7] = acc[7] * inv + bv1.w;
    if (!FINAL) {
        uint4 rv = *((const uint4*)(resb + ((size_t)node << 7)) + j);
        float rr[8] = {bf2f_lo(rv.x), bf2f_hi(rv.x), bf2f_lo(rv.y), bf2f_hi(rv.y),
                       bf2f_lo(rv.z), bf2f_hi(rv.z), bf2f_lo(rv.w), bf2f_hi(rv.w)};
#pragma unroll
        for (int c = 0; c < 8; ++c) {
            float vv = val[c];
            float ev = __expf(vv) - 1.f;
            val[c] = ((vv > 0.f) ? vv : ev) + rr[c];
        }
    }
    float s2 = 0.f;
#pragma unroll
    for (int c = 0; c < 8; ++c) s2 += val[c];
#pragma unroll
    for (int off = 1; off < 16; off <<= 1) s2 += __shfl_xor(s2, off, 64);
    float mean = s2 * (1.f / 128.f);
    float q = 0.f;
    float dd[8];
#pragma unroll
    for (int c = 0; c < 8; ++c) {
        dd[c] = val[c] - mean;
        q += dd[c] * dd[c];
    }
#pragma unroll
    for (int off = 1; off < 16; off <<= 1) q += __shfl_xor(q, off, 64);
    float r = rsqrtf(q * (1.f / 128.f) + 1e-5f);
    if (g == 0) {
        if (FINAL) {
            float* op = outf + ((size_t)node << 7) + c0;
            *(float4*)op = make_float4(dd[0] * r, dd[1] * r, dd[2] * r, dd[3] * r);
            *(float4*)(op + 4) = make_float4(dd[4] * r, dd[5] * r, dd[6] * r, dd[7] * r);
        } else {
            uint4 u;
            u.x = (uint_t)f2bf(dd[0] * r) | ((uint_t)f2bf(dd[1] * r) << 16);
            u.y = (uint_t)f2bf(dd[2] * r) | ((uint_t)f2bf(dd[3] * r) << 16);
            u.z = (uint_t)f2bf(dd[4] * r) | ((uint_t)f2bf(dd[5] * r) << 16);
            u.w = (uint_t)f2bf(dd[6] * r) | ((uint_t)f2bf(dd[7] * r) << 16);
            *((uint4*)(outb + ((size_t)node << 7)) + j) = u;
        }
    }
}

// ---------------------------------------------------------------------------
extern "C" void kernel_launch(void* const* d_in, const int* in_sizes, int n_in,
                              void* d_out, int out_size, void* d_ws, size_t ws_size,
                              hipStream_t stream) {
    const int N = in_sizes[0] / 128;
    const int E = in_sizes[1] / 2;
    const int Etot = E + N;
    const int NB = (N + BCK - 1) / BCK;
    const int NBLK = (Etot + EPB - 1) / EPB;

    const float* x    = (const float*)d_in[0];
    const int*   ei   = (const int*)d_in[1];
    const float* W_in = (const float*)d_in[2];
    const float* b_in = (const float*)d_in[3];
    const float* W0   = (const float*)d_in[4];
    const float* as0  = (const float*)d_in[5];
    const float* ad0  = (const float*)d_in[6];
    const float* b0   = (const float*)d_in[7];
    const float* W1   = (const float*)d_in[8];
    const float* as1  = (const float*)d_in[9];
    const float* ad1  = (const float*)d_in[10];
    const float* b1   = (const float*)d_in[11];
    const float* W2   = (const float*)d_in[12];
    const float* as2  = (const float*)d_in[13];
    const float* ad2  = (const float*)d_in[14];
    const float* b2   = (const float*)d_in[15];

    char* wsp = (char*)d_ws;
    size_t off = 0;
    auto carve = [&](size_t bytes) -> void* {
        void* p = wsp + off;
        off += (bytes + 255) & ~(size_t)255;
        return p;
    };
    ushort_t* hAb  = (ushort_t*)carve((size_t)N * 128 * 2);
    ushort_t* hBb  = (ushort_t*)carve((size_t)N * 128 * 2);
    ushort_t* hWb  = (ushort_t*)carve((size_t)N * 128 * 2);
    float*    alS  = (float*)carve((size_t)N * 4 * 4);
    float*    alD  = (float*)carve((size_t)N * 4 * 4);
    int*      rowp = (int*)carve((size_t)(N + 1) * 4);
    int*      csrc = (int*)carve((size_t)Etot * 4);
    int*      bhist= (int*)carve((size_t)NBLK * 256 * 4);
    int*      obase= (int*)carve((size_t)NBLK * 256 * 4);
    int*      gbase= (int*)carve((size_t)257 * 4);
    int*      gtot = (int*)carve((size_t)256 * 4);
    ushort_t* BfIn = (ushort_t*)carve((size_t)4 * 8 * 64 * 8 * 2);
    ushort_t* Bf0  = (ushort_t*)carve((size_t)4 * 9 * 64 * 8 * 2);
    ushort_t* Bf1  = (ushort_t*)carve((size_t)4 * 9 * 64 * 8 * 2);
    ushort_t* Bf2  = (ushort_t*)carve((size_t)4 * 9 * 64 * 8 * 2);
    // pairs aliases hWb: lifetime ends (bucket_csr) before hWb is written (gemm<1>)
    uint2*    pairs = (uint2*)hWb;
    (void)ws_size; (void)n_in; (void)out_size;

    // bfrag x4 + per-block histograms (atomic-free)
    prep_kernel<<<35 + NBLK, 256, 0, stream>>>(W_in, W0, as0, ad0, W1, as1, ad1,
                                               W2, as2, ad2, BfIn, Bf0, Bf1, Bf2,
                                               ei, bhist, E, N);
    csr_scan1<<<256, 256, 0, stream>>>(bhist, obase, gtot, NBLK);
    csr_scan2<<<1, 256, 0, stream>>>(gtot, gbase, rowp, N, Etot);
    csr_scatter<<<NBLK, 256, 0, stream>>>(ei, gbase, obase, pairs, E, N);
    bucket_csr<<<NB, 256, 0, stream>>>(pairs, gbase, rowp, csrc, N);

    int gg = (N + 127) / 128;
    int ga = (N + 3) / 4;

    // h = relu(x @ W_in + b_in) -> bf16
    gemm_mfma<0><<<gg, 256, 0, stream>>>(x, nullptr, BfIn, b_in, hAb,
                                         nullptr, nullptr, N);
    // Layer 0
    gemm_mfma<1><<<gg, 256, 0, stream>>>(nullptr, hAb, Bf0, nullptr, hWb, alS, alD, N);
    gat_aggregate<4, 0><<<ga, 256, 0, stream>>>(hWb, alS, alD, rowp, csrc, b0,
                                                hAb, hBb, nullptr, N);
    // Layer 1
    gemm_mfma<1><<<gg, 256, 0, stream>>>(nullptr, hBb, Bf1, nullptr, hWb, alS, alD, N);
    gat_aggregate<4, 0><<<ga, 256, 0, stream>>>(hWb, alS, alD, rowp, csrc, b1,
                                                hBb, hAb, nullptr, N);
    // Layer 2 (heads=1)
    gemm_mfma<2><<<gg, 256, 0, stream>>>(nullptr, hAb, Bf2, nullptr, hWb, alS, alD, N);
    gat_aggregate<1, 1><<<ga, 256, 0, stream>>>(hWb, alS, alD, rowp, csrc, b2,
                                                nullptr, nullptr, (float*)d_out, N);
}